// Round 9
// baseline (1018.715 us; speedup 1.0000x reference)
//
#include <hip/hip_runtime.h>

#define NN 100000
#define CC 128
#define EE 200000
#define TT 3
#define NCHUNK 98   // ceil(NN/1024)

typedef __attribute__((ext_vector_type(8))) __bf16 bf16x8;
typedef __attribute__((ext_vector_type(8))) unsigned short ushort8;
typedef __attribute__((ext_vector_type(4))) float f32x4;

union U8 { ushort8 u; bf16x8 b; };

__device__ __forceinline__ unsigned short f2bf(float v) {
    unsigned u = __float_as_uint(v);
    u += 0x7fffu + ((u >> 16) & 1u);          // RNE
    return (unsigned short)(u >> 16);
}
__device__ __forceinline__ float bf2f(unsigned short h) {
    return __uint_as_float(((unsigned)h) << 16);
}
// split 8 fp32 into hi/lo bf16 fragments (a ~= hi + lo)
__device__ __forceinline__ void split8(const float* f, bf16x8& hi, bf16x8& lo) {
    U8 h, l;
    #pragma unroll
    for (int j = 0; j < 8; ++j) {
        float v = f[j];
        unsigned short hs = f2bf(v);
        h.u[j] = hs;
        l.u[j] = f2bf(v - bf2f(hs));
    }
    hi = h.b; lo = l.b;
}

// load one A row-tile k-slice (8 fp32) and split
__device__ __forceinline__ void loadA(const float* __restrict__ X, int arow, int kt, int kb,
                                      bf16x8& hi, bf16x8& lo) {
    float tmp[8];
    if (arow < NN) {
        const float* xp = X + (size_t)arow * CC + kt * 32 + kb * 8;
        float4 p0 = *(const float4*)xp;
        float4 p1 = *(const float4*)(xp + 4);
        tmp[0] = p0.x; tmp[1] = p0.y; tmp[2] = p0.z; tmp[3] = p0.w;
        tmp[4] = p1.x; tmp[5] = p1.y; tmp[6] = p1.z; tmp[7] = p1.w;
    } else {
        #pragma unroll
        for (int j = 0; j < 8; ++j) tmp[j] = 0.f;
    }
    split8(tmp, hi, lo);
}

// fragment-major offset: frag (kt,nt), lane l, elem j  ->  ((kt*8+nt)*64+l)*8+j
// holds W[c][k] with c = nt*16+(l&15), k = kt*32+(l>>4)*8+j

// ---------------- pack: split W into bf16 hi/lo FRAGMENT-MAJOR ----------------
__global__ __launch_bounds__(256) void k_pack(
    const float* __restrict__ Wq, const float* __restrict__ bq,
    const float* __restrict__ Wk, const float* __restrict__ bk,
    const float* __restrict__ Wv, const float* __restrict__ bv,
    const float* __restrict__ Wf,
    unsigned short* __restrict__ Whi3, unsigned short* __restrict__ Wlo3,
    unsigned short* __restrict__ Wfhi, unsigned short* __restrict__ Wflo,
    float* __restrict__ Bpack)
{
    int idx = blockIdx.x * 256 + threadIdx.x;   // 0..16383
    int y = blockIdx.y;                          // 0..12
    int j  = idx & 7;
    int l  = (idx >> 3) & 63;
    int nt = (idx >> 9) & 7;
    int kt = idx >> 12;
    int c = nt * 16 + (l & 15);
    int k = kt * 32 + ((l >> 4) << 3) + j;
    if (y < 9) {
        int t = y / 3, m = y % 3;
        const float* W = (m == 0 ? Wq : m == 1 ? Wk : Wv) + t * CC * CC;
        float v = W[c * CC + k];
        unsigned short hs = f2bf(v);
        Whi3[y * CC * CC + idx] = hs;
        Wlo3[y * CC * CC + idx] = f2bf(v - bf2f(hs));
    } else if (y < 12) {
        int t = y - 9;
        float v = Wf[(size_t)c * (TT * CC) + t * CC + k];
        unsigned short hs = f2bf(v);
        Wfhi[t * CC * CC + idx] = hs;
        Wflo[t * CC * CC + idx] = f2bf(v - bf2f(hs));
    } else {
        if (idx < 9 * CC) {
            int mm = idx >> 7, cc2 = idx & 127;
            int t = mm / 3, m = mm % 3;
            const float* b = (m == 0 ? bq : m == 1 ? bk : bv);
            Bpack[idx] = b[t * CC + cc2];
        }
    }
}

// ---------------- Wcomb (skip path folded), FRAGMENT-MAJOR; bconst fp32 ----------------
__global__ __launch_bounds__(256) void k_wcomb(
    const float* __restrict__ Ws, const float* __restrict__ bs,
    const float* __restrict__ Wf, const float* __restrict__ bf,
    unsigned short* __restrict__ Wch, unsigned short* __restrict__ Wcl,
    float* __restrict__ bconst)
{
    int b = blockIdx.x;
    if (b < 64) {
        int idx = b * 256 + threadIdx.x;
        int k = idx >> 7, c = idx & 127;
        float s = 0.f;
        for (int t = 0; t < TT; ++t) {
            const float* wsp = Ws + t * CC * CC;
            const float* wfp = Wf + (size_t)c * (TT * CC) + t * CC;
            for (int j = 0; j < CC; ++j)
                s += wsp[j * CC + k] * wfp[j];
        }
        int kt = k >> 5, kb = (k >> 3) & 3, j = k & 7;
        int l = (c & 15) + (kb << 4);
        int nt = c >> 4;
        int o = (((kt * 8 + nt) * 64) + l) * 8 + j;
        unsigned short hs = f2bf(s);
        Wch[o] = hs;
        Wcl[o] = f2bf(s - bf2f(hs));
    } else {
        int c = threadIdx.x;
        if (c < CC) {
            float s = bf[c];
            for (int t = 0; t < TT; ++t) {
                const float* wfp = Wf + (size_t)c * (TT * CC) + t * CC;
                for (int j = 0; j < CC; ++j)
                    s += bs[t * CC + j] * wfp[j];
            }
            bconst[c] = s;
        }
    }
}

// ---------------- CSR build (unchanged) ----------------
__global__ __launch_bounds__(256) void k_count(const int* __restrict__ dst, int* __restrict__ deg) {
    int idx = blockIdx.x * 256 + threadIdx.x;
    if (idx >= TT * EE) return;
    int t = idx / EE;
    atomicAdd(&deg[t * NN + dst[idx]], 1);
}

__global__ __launch_bounds__(256) void k_scan1(const int* __restrict__ deg,
                                               int* __restrict__ incl, int* __restrict__ bsums) {
    int t = blockIdx.y, b = blockIdx.x, tid = threadIdx.x;
    const int* d = deg + t * NN;
    int base = b * 1024 + tid * 4;
    int v0 = (base + 0 < NN) ? d[base + 0] : 0;
    int v1 = (base + 1 < NN) ? d[base + 1] : 0;
    int v2 = (base + 2 < NN) ? d[base + 2] : 0;
    int v3 = (base + 3 < NN) ? d[base + 3] : 0;
    v1 += v0; v2 += v1; v3 += v2;
    __shared__ int lds[256];
    lds[tid] = v3;
    for (int off = 1; off < 256; off <<= 1) {
        __syncthreads();
        int x = (tid >= off) ? lds[tid - off] : 0;
        __syncthreads();
        lds[tid] += x;
    }
    __syncthreads();
    int excl = lds[tid] - v3;
    if (base + 0 < NN) incl[t * NN + base + 0] = excl + v0;
    if (base + 1 < NN) incl[t * NN + base + 1] = excl + v1;
    if (base + 2 < NN) incl[t * NN + base + 2] = excl + v2;
    if (base + 3 < NN) incl[t * NN + base + 3] = excl + v3;
    if (tid == 255) bsums[t * NCHUNK + b] = lds[255];
}

__global__ __launch_bounds__(128) void k_scan2(const int* __restrict__ bsums, int* __restrict__ bexcl) {
    int t = blockIdx.y, tid = threadIdx.x;
    __shared__ int lds[128];
    int v = (tid < NCHUNK) ? bsums[t * NCHUNK + tid] : 0;
    lds[tid] = v;
    for (int off = 1; off < 128; off <<= 1) {
        __syncthreads();
        int x = (tid >= off) ? lds[tid - off] : 0;
        __syncthreads();
        lds[tid] += x;
    }
    if (tid < NCHUNK) bexcl[t * NCHUNK + tid] = lds[tid] - v;
}

__global__ __launch_bounds__(256) void k_scan3(const int* __restrict__ deg, const int* __restrict__ incl,
                                               const int* __restrict__ bexcl,
                                               int* __restrict__ offs, int* __restrict__ cursor) {
    int t = blockIdx.y, b = blockIdx.x, tid = threadIdx.x;
    int add = bexcl[t * NCHUNK + b];
    int base = b * 1024 + tid * 4;
    #pragma unroll
    for (int j = 0; j < 4; j++) {
        int i = base + j;
        if (i < NN) {
            int e = incl[t * NN + i] - deg[t * NN + i] + add;
            offs[t * NN + i] = e;
            cursor[t * NN + i] = e;
        }
    }
}

__global__ __launch_bounds__(256) void k_scatter(const int* __restrict__ src, const int* __restrict__ dst,
                                                 int* __restrict__ cursor, int* __restrict__ csr_src) {
    int idx = blockIdx.x * 256 + threadIdx.x;
    if (idx >= TT * EE) return;
    int t = idx / EE;
    int d = dst[idx];
    int pos = atomicAdd(&cursor[t * NN + d], 1);
    csr_src[t * EE + pos] = src[idx];
}

// stage 32KB (16384 ushorts) from global into LDS, whole block
__device__ __forceinline__ void stage32k(unsigned short* lw, const unsigned short* __restrict__ src, int tid) {
    #pragma unroll
    for (int i = 0; i < 8; ++i) {
        int o = i * 2048 + tid * 8;
        *(ushort8*)&lw[o] = *(const ushort8*)(src + o);
    }
}

// ---------------- split-bf16 MFMA with LDS-staged weights: Q,K,V. 128 rows/block ----------------
__global__ __launch_bounds__(256, 4) void k_mg3(
    const float* __restrict__ x,
    const unsigned short* __restrict__ Whi, const unsigned short* __restrict__ Wlo,
    const float* __restrict__ B3,
    float* __restrict__ Q, float* __restrict__ K, float* __restrict__ V)
{
    __shared__ __align__(16) unsigned short lw[CC * CC];   // 32KB: one hi or lo half of one mat
    int tid = threadIdx.x;
    int wid = tid >> 6, l = tid & 63;
    int lan = l & 15, kb = l >> 4;
    int rb = blockIdx.x * 128 + wid * 32;

    // A fragments: 2 row-tiles x 4 k-tiles (per-wave, registers)
    bf16x8 ah[2][4], al[2][4];
    #pragma unroll
    for (int rt = 0; rt < 2; ++rt)
        #pragma unroll
        for (int kt = 0; kt < 4; ++kt)
            loadA(x, rb + rt * 16 + lan, kt, kb, ah[rt][kt], al[rt][kt]);

    #pragma unroll 1
    for (int m = 0; m < 3; ++m) {
        f32x4 acc[2][8];
        #pragma unroll
        for (int rt = 0; rt < 2; ++rt)
            #pragma unroll
            for (int nt = 0; nt < 8; ++nt)
                #pragma unroll
                for (int i = 0; i < 4; ++i) acc[rt][nt][i] = 0.f;

        // ---- hi half: acc += al*bh + ah*bh ----
        __syncthreads();
        stage32k(lw, Whi + m * CC * CC, tid);
        __syncthreads();
        #pragma unroll
        for (int kt = 0; kt < 4; ++kt)
            #pragma unroll
            for (int nt = 0; nt < 8; ++nt) {
                U8 b;
                b.u = *(const ushort8*)&lw[((kt * 8 + nt) * 64 + l) * 8];
                #pragma unroll
                for (int rt = 0; rt < 2; ++rt) {
                    acc[rt][nt] = __builtin_amdgcn_mfma_f32_16x16x32_bf16(al[rt][kt], b.b, acc[rt][nt], 0, 0, 0);
                    acc[rt][nt] = __builtin_amdgcn_mfma_f32_16x16x32_bf16(ah[rt][kt], b.b, acc[rt][nt], 0, 0, 0);
                }
            }

        // ---- lo half: acc += ah*bl ----
        __syncthreads();
        stage32k(lw, Wlo + m * CC * CC, tid);
        __syncthreads();
        #pragma unroll
        for (int kt = 0; kt < 4; ++kt)
            #pragma unroll
            for (int nt = 0; nt < 8; ++nt) {
                U8 b;
                b.u = *(const ushort8*)&lw[((kt * 8 + nt) * 64 + l) * 8];
                #pragma unroll
                for (int rt = 0; rt < 2; ++rt)
                    acc[rt][nt] = __builtin_amdgcn_mfma_f32_16x16x32_bf16(ah[rt][kt], b.b, acc[rt][nt], 0, 0, 0);
            }

        float* dst = (m == 0 ? Q : m == 1 ? K : V);
        #pragma unroll
        for (int nt = 0; nt < 8; ++nt) {
            int col = nt * 16 + lan;
            float bias = B3[m * CC + col];
            #pragma unroll
            for (int rt = 0; rt < 2; ++rt)
                #pragma unroll
                for (int i = 0; i < 4; ++i) {
                    int grow = rb + rt * 16 + kb * 4 + i;   // D: row=(l>>4)*4+reg, col=l&15 [m89]
                    if (grow < NN)
                        dst[(size_t)grow * CC + col] = acc[rt][nt][i] + bias;
                }
        }
    }
}

// ---------------- split-bf16 MFMA fusion with LDS-staged weights ----------------
__global__ __launch_bounds__(256, 4) void k_mfuse(
    const float* __restrict__ X0,
    const unsigned short* __restrict__ W0h, const unsigned short* __restrict__ W0l,
    const float* __restrict__ X1,
    const unsigned short* __restrict__ W1h, const unsigned short* __restrict__ W1l,
    const float* __restrict__ bias, float* __restrict__ out, int accum)
{
    __shared__ __align__(16) unsigned short lw[CC * CC];
    int tid = threadIdx.x;
    int wid = tid >> 6, l = tid & 63;
    int lan = l & 15, kb = l >> 4;
    int rb = blockIdx.x * 128 + wid * 32;

    f32x4 acc[2][8];
    #pragma unroll
    for (int rt = 0; rt < 2; ++rt)
        #pragma unroll
        for (int nt = 0; nt < 8; ++nt)
            #pragma unroll
            for (int i = 0; i < 4; ++i) acc[rt][nt][i] = 0.f;

    #pragma unroll 1
    for (int s = 0; s < 2; ++s) {
        const float* X = s ? X1 : X0;
        if (!X) break;
        const unsigned short* wh = s ? W1h : W0h;
        const unsigned short* wl = s ? W1l : W0l;

        bf16x8 ah[2][4], al[2][4];
        #pragma unroll
        for (int rt = 0; rt < 2; ++rt)
            #pragma unroll
            for (int kt = 0; kt < 4; ++kt)
                loadA(X, rb + rt * 16 + lan, kt, kb, ah[rt][kt], al[rt][kt]);

        __syncthreads();
        stage32k(lw, wh, tid);
        __syncthreads();
        #pragma unroll
        for (int kt = 0; kt < 4; ++kt)
            #pragma unroll
            for (int nt = 0; nt < 8; ++nt) {
                U8 b;
                b.u = *(const ushort8*)&lw[((kt * 8 + nt) * 64 + l) * 8];
                #pragma unroll
                for (int rt = 0; rt < 2; ++rt) {
                    acc[rt][nt] = __builtin_amdgcn_mfma_f32_16x16x32_bf16(al[rt][kt], b.b, acc[rt][nt], 0, 0, 0);
                    acc[rt][nt] = __builtin_amdgcn_mfma_f32_16x16x32_bf16(ah[rt][kt], b.b, acc[rt][nt], 0, 0, 0);
                }
            }

        __syncthreads();
        stage32k(lw, wl, tid);
        __syncthreads();
        #pragma unroll
        for (int kt = 0; kt < 4; ++kt)
            #pragma unroll
            for (int nt = 0; nt < 8; ++nt) {
                U8 b;
                b.u = *(const ushort8*)&lw[((kt * 8 + nt) * 64 + l) * 8];
                #pragma unroll
                for (int rt = 0; rt < 2; ++rt)
                    acc[rt][nt] = __builtin_amdgcn_mfma_f32_16x16x32_bf16(ah[rt][kt], b.b, acc[rt][nt], 0, 0, 0);
            }
    }

    #pragma unroll
    for (int nt = 0; nt < 8; ++nt) {
        int col = nt * 16 + lan;
        #pragma unroll
        for (int rt = 0; rt < 2; ++rt)
            #pragma unroll
            for (int i = 0; i < 4; ++i) {
                int grow = rb + rt * 16 + kb * 4 + i;
                if (grow < NN) {
                    float* op = out + (size_t)grow * CC + col;
                    float v = acc[rt][nt][i];
                    v += accum ? *op : bias[col];
                    *op = v;
                }
            }
    }
}

// ---------------- per-node attention aggregation -> A fp32 (unchanged) ----------------
__global__ __launch_bounds__(256) void k_agg(
    const float* __restrict__ Q, const float* __restrict__ Kx,
    const float* __restrict__ V, float* __restrict__ A,
    const int* __restrict__ offs, const int* __restrict__ deg, const int* __restrict__ csr)
{
    int wid = threadIdx.x >> 6;
    int lane = threadIdx.x & 63;
    int n = blockIdx.x * 4 + wid;
    if (n >= NN) return;
    int dg = deg[n];
    if (dg == 0) {
        A[(size_t)n * CC + lane] = 0.f;
        A[(size_t)n * CC + 64 + lane] = 0.f;
        return;
    }
    const float scale = 0.17677669529663687f;  // 1/sqrt(32)
    float q0 = Q[(size_t)n * CC + lane];
    float q1 = Q[(size_t)n * CC + 64 + lane];
    float acc0 = 0.f, acc1 = 0.f, den0 = 0.f, den1 = 0.f;
    int off = offs[n];
    for (int i = 0; i < dg; i++) {
        int s = csr[off + i];
        const float* kb = Kx + (size_t)s * CC;
        const float* vb = V + (size_t)s * CC;
        float k0 = kb[lane], k1 = kb[64 + lane];
        float v0 = vb[lane], v1 = vb[64 + lane];
        float d0 = q0 * k0, d1 = q1 * k1;
        #pragma unroll
        for (int m = 16; m >= 1; m >>= 1) {
            d0 += __shfl_xor(d0, m);
            d1 += __shfl_xor(d1, m);
        }
        float e0 = expf(d0 * scale), e1 = expf(d1 * scale);
        acc0 += e0 * v0; den0 += e0;
        acc1 += e1 * v1; den1 += e1;
    }
    A[(size_t)n * CC + lane]      = acc0 / (den0 + 1e-16f);
    A[(size_t)n * CC + 64 + lane] = acc1 / (den1 + 1e-16f);
}

extern "C" void kernel_launch(void* const* d_in, const int* in_sizes, int n_in,
                              void* d_out, int out_size, void* d_ws, size_t ws_size,
                              hipStream_t stream)
{
    const float* x   = (const float*)d_in[0];
    const int*   src = (const int*)d_in[1];
    const int*   dst = (const int*)d_in[2];
    const float* Wq  = (const float*)d_in[3];
    const float* bq  = (const float*)d_in[4];
    const float* Wk  = (const float*)d_in[5];
    const float* bk  = (const float*)d_in[6];
    const float* Wv  = (const float*)d_in[7];
    const float* bv  = (const float*)d_in[8];
    const float* Ws  = (const float*)d_in[9];
    const float* bs  = (const float*)d_in[10];
    const float* Wf  = (const float*)d_in[11];
    const float* bf  = (const float*)d_in[12];
    float* out = (float*)d_out;

    char* ws = (char*)d_ws;
    size_t o = 0;
    auto alloc = [&](size_t bytes) -> char* {
        char* p = ws + o;
        o = (o + bytes + 255) & ~(size_t)255;
        return p;
    };
    unsigned short* Whi3 = (unsigned short*)alloc((size_t)9 * CC * CC * 2);
    unsigned short* Wlo3 = (unsigned short*)alloc((size_t)9 * CC * CC * 2);
    unsigned short* Wfhi = (unsigned short*)alloc((size_t)TT * CC * CC * 2);
    unsigned short* Wflo = (unsigned short*)alloc((size_t)TT * CC * CC * 2);
    unsigned short* Wch  = (unsigned short*)alloc((size_t)CC * CC * 2);
    unsigned short* Wcl  = (unsigned short*)alloc((size_t)CC * CC * 2);
    float* Bpack  = (float*)alloc((size_t)9 * CC * 4);
    float* bconst = (float*)alloc((size_t)CC * 4);
    int* deg      = (int*)alloc((size_t)TT * NN * 4);
    int* incl     = (int*)alloc((size_t)TT * NN * 4);
    int* bsums    = (int*)alloc((size_t)TT * NCHUNK * 4);
    int* bexcl    = (int*)alloc((size_t)TT * NCHUNK * 4);
    int* offs     = (int*)alloc((size_t)TT * NN * 4);
    int* cursor   = (int*)alloc((size_t)TT * NN * 4);
    int* csr_src  = (int*)alloc((size_t)TT * EE * 4);
    float* Qb = (float*)alloc((size_t)NN * CC * 4);
    float* Kb = (float*)alloc((size_t)NN * CC * 4);
    float* Vb = (float*)alloc((size_t)NN * CC * 4);
    float* Ab = (float*)alloc((size_t)NN * CC * 4);

    hipMemsetAsync(deg, 0, (size_t)TT * NN * 4, stream);
    k_pack<<<dim3(64, 13), 256, 0, stream>>>(Wq, bq, Wk, bk, Wv, bv, Wf,
                                             Whi3, Wlo3, Wfhi, Wflo, Bpack);
    k_wcomb<<<65, 256, 0, stream>>>(Ws, bs, Wf, bf, Wch, Wcl, bconst);
    k_count<<<(TT * EE + 255) / 256, 256, 0, stream>>>(dst, deg);
    k_scan1<<<dim3(NCHUNK, TT), 256, 0, stream>>>(deg, incl, bsums);
    k_scan2<<<dim3(1, TT), 128, 0, stream>>>(bsums, bexcl);
    k_scan3<<<dim3(NCHUNK, TT), 256, 0, stream>>>(deg, incl, bexcl, offs, cursor);
    k_scatter<<<(TT * EE + 255) / 256, 256, 0, stream>>>(src, dst, cursor, csr_src);

    int gblocks = (NN + 127) / 128;   // 782
    for (int t = 0; t < TT; t++) {
        k_mg3<<<gblocks, 256, 0, stream>>>(x, Whi3 + (size_t)t * 3 * CC * CC,
                                           Wlo3 + (size_t)t * 3 * CC * CC,
                                           Bpack + t * 3 * CC, Qb, Kb, Vb);
        k_agg<<<(NN + 3) / 4, 256, 0, stream>>>(Qb, Kb, Vb, Ab,
                                                offs + t * NN, deg + t * NN, csr_src + (size_t)t * EE);
        if (t == 0)
            k_mfuse<<<gblocks, 256, 0, stream>>>(x, Wch, Wcl,
                                                 Ab, Wfhi, Wflo,
                                                 bconst, out, 0);
        else
            k_mfuse<<<gblocks, 256, 0, stream>>>(Ab, Wfhi + (size_t)t * CC * CC, Wflo + (size_t)t * CC * CC,
                                                 nullptr, nullptr, nullptr,
                                                 bconst, out, 1);
    }
}

// Round 10
// 918.494 us; speedup vs baseline: 1.1091x; 1.1091x over previous
//
#include <hip/hip_runtime.h>

#define NN 100000
#define CC 128
#define EE 200000
#define TT 3
#define NCHUNK 98   // ceil(NN/1024)

typedef __attribute__((ext_vector_type(8))) __bf16 bf16x8;
typedef __attribute__((ext_vector_type(8))) unsigned short ushort8;
typedef __attribute__((ext_vector_type(4))) float f32x4;

union U8 { ushort8 u; bf16x8 b; };

__device__ __forceinline__ unsigned short f2bf(float v) {
    unsigned u = __float_as_uint(v);
    u += 0x7fffu + ((u >> 16) & 1u);          // RNE
    return (unsigned short)(u >> 16);
}
__device__ __forceinline__ float bf2f(unsigned short h) {
    return __uint_as_float(((unsigned)h) << 16);
}
// split 8 fp32 into hi/lo bf16 fragments (a ~= hi + lo)
__device__ __forceinline__ void split8(const float* f, bf16x8& hi, bf16x8& lo) {
    U8 h, l;
    #pragma unroll
    for (int j = 0; j < 8; ++j) {
        float v = f[j];
        unsigned short hs = f2bf(v);
        h.u[j] = hs;
        l.u[j] = f2bf(v - bf2f(hs));
    }
    hi = h.b; lo = l.b;
}

// load one A row-tile k-slice (8 fp32) and split
__device__ __forceinline__ void loadA(const float* __restrict__ X, int arow, int kt, int kb,
                                      bf16x8& hi, bf16x8& lo) {
    float tmp[8];
    if (arow < NN) {
        const float* xp = X + (size_t)arow * CC + kt * 32 + kb * 8;
        float4 p0 = *(const float4*)xp;
        float4 p1 = *(const float4*)(xp + 4);
        tmp[0] = p0.x; tmp[1] = p0.y; tmp[2] = p0.z; tmp[3] = p0.w;
        tmp[4] = p1.x; tmp[5] = p1.y; tmp[6] = p1.z; tmp[7] = p1.w;
    } else {
        #pragma unroll
        for (int j = 0; j < 8; ++j) tmp[j] = 0.f;
    }
    split8(tmp, hi, lo);
}

// fragment-major offset: frag (kt,nt), lane l, elem j  ->  ((kt*8+nt)*64+l)*8+j
// holds W[c][k] with c = nt*16+(l&15), k = kt*32+(l>>4)*8+j

// ---------------- pack: split W into bf16 hi/lo FRAGMENT-MAJOR ----------------
__global__ __launch_bounds__(256) void k_pack(
    const float* __restrict__ Wq, const float* __restrict__ bq,
    const float* __restrict__ Wk, const float* __restrict__ bk,
    const float* __restrict__ Wv, const float* __restrict__ bv,
    const float* __restrict__ Wf,
    unsigned short* __restrict__ Whi3, unsigned short* __restrict__ Wlo3,
    unsigned short* __restrict__ Wfhi, unsigned short* __restrict__ Wflo,
    float* __restrict__ Bpack)
{
    int idx = blockIdx.x * 256 + threadIdx.x;   // 0..16383
    int y = blockIdx.y;                          // 0..12
    int j  = idx & 7;
    int l  = (idx >> 3) & 63;
    int nt = (idx >> 9) & 7;
    int kt = idx >> 12;
    int c = nt * 16 + (l & 15);
    int k = kt * 32 + ((l >> 4) << 3) + j;
    if (y < 9) {
        int t = y / 3, m = y % 3;
        const float* W = (m == 0 ? Wq : m == 1 ? Wk : Wv) + t * CC * CC;
        float v = W[c * CC + k];
        unsigned short hs = f2bf(v);
        Whi3[y * CC * CC + idx] = hs;
        Wlo3[y * CC * CC + idx] = f2bf(v - bf2f(hs));
    } else if (y < 12) {
        int t = y - 9;
        float v = Wf[(size_t)c * (TT * CC) + t * CC + k];
        unsigned short hs = f2bf(v);
        Wfhi[t * CC * CC + idx] = hs;
        Wflo[t * CC * CC + idx] = f2bf(v - bf2f(hs));
    } else {
        if (idx < 9 * CC) {
            int mm = idx >> 7, cc2 = idx & 127;
            int t = mm / 3, m = mm % 3;
            const float* b = (m == 0 ? bq : m == 1 ? bk : bv);
            Bpack[idx] = b[t * CC + cc2];
        }
    }
}

// ---------------- Wcomb (skip path folded), FRAGMENT-MAJOR; bconst fp32 ----------------
__global__ __launch_bounds__(256) void k_wcomb(
    const float* __restrict__ Ws, const float* __restrict__ bs,
    const float* __restrict__ Wf, const float* __restrict__ bf,
    unsigned short* __restrict__ Wch, unsigned short* __restrict__ Wcl,
    float* __restrict__ bconst)
{
    int b = blockIdx.x;
    if (b < 64) {
        int idx = b * 256 + threadIdx.x;
        int k = idx >> 7, c = idx & 127;
        float s = 0.f;
        for (int t = 0; t < TT; ++t) {
            const float* wsp = Ws + t * CC * CC;
            const float* wfp = Wf + (size_t)c * (TT * CC) + t * CC;
            for (int j = 0; j < CC; ++j)
                s += wsp[j * CC + k] * wfp[j];
        }
        int kt = k >> 5, kb = (k >> 3) & 3, j = k & 7;
        int l = (c & 15) + (kb << 4);
        int nt = c >> 4;
        int o = (((kt * 8 + nt) * 64) + l) * 8 + j;
        unsigned short hs = f2bf(s);
        Wch[o] = hs;
        Wcl[o] = f2bf(s - bf2f(hs));
    } else {
        int c = threadIdx.x;
        if (c < CC) {
            float s = bf[c];
            for (int t = 0; t < TT; ++t) {
                const float* wfp = Wf + (size_t)c * (TT * CC) + t * CC;
                for (int j = 0; j < CC; ++j)
                    s += bs[t * CC + j] * wfp[j];
            }
            bconst[c] = s;
        }
    }
}

// ---------------- CSR build (unchanged) ----------------
__global__ __launch_bounds__(256) void k_count(const int* __restrict__ dst, int* __restrict__ deg) {
    int idx = blockIdx.x * 256 + threadIdx.x;
    if (idx >= TT * EE) return;
    int t = idx / EE;
    atomicAdd(&deg[t * NN + dst[idx]], 1);
}

__global__ __launch_bounds__(256) void k_scan1(const int* __restrict__ deg,
                                               int* __restrict__ incl, int* __restrict__ bsums) {
    int t = blockIdx.y, b = blockIdx.x, tid = threadIdx.x;
    const int* d = deg + t * NN;
    int base = b * 1024 + tid * 4;
    int v0 = (base + 0 < NN) ? d[base + 0] : 0;
    int v1 = (base + 1 < NN) ? d[base + 1] : 0;
    int v2 = (base + 2 < NN) ? d[base + 2] : 0;
    int v3 = (base + 3 < NN) ? d[base + 3] : 0;
    v1 += v0; v2 += v1; v3 += v2;
    __shared__ int lds[256];
    lds[tid] = v3;
    for (int off = 1; off < 256; off <<= 1) {
        __syncthreads();
        int x = (tid >= off) ? lds[tid - off] : 0;
        __syncthreads();
        lds[tid] += x;
    }
    __syncthreads();
    int excl = lds[tid] - v3;
    if (base + 0 < NN) incl[t * NN + base + 0] = excl + v0;
    if (base + 1 < NN) incl[t * NN + base + 1] = excl + v1;
    if (base + 2 < NN) incl[t * NN + base + 2] = excl + v2;
    if (base + 3 < NN) incl[t * NN + base + 3] = excl + v3;
    if (tid == 255) bsums[t * NCHUNK + b] = lds[255];
}

__global__ __launch_bounds__(128) void k_scan2(const int* __restrict__ bsums, int* __restrict__ bexcl) {
    int t = blockIdx.y, tid = threadIdx.x;
    __shared__ int lds[128];
    int v = (tid < NCHUNK) ? bsums[t * NCHUNK + tid] : 0;
    lds[tid] = v;
    for (int off = 1; off < 128; off <<= 1) {
        __syncthreads();
        int x = (tid >= off) ? lds[tid - off] : 0;
        __syncthreads();
        lds[tid] += x;
    }
    if (tid < NCHUNK) bexcl[t * NCHUNK + tid] = lds[tid] - v;
}

__global__ __launch_bounds__(256) void k_scan3(const int* __restrict__ deg, const int* __restrict__ incl,
                                               const int* __restrict__ bexcl,
                                               int* __restrict__ offs, int* __restrict__ cursor) {
    int t = blockIdx.y, b = blockIdx.x, tid = threadIdx.x;
    int add = bexcl[t * NCHUNK + b];
    int base = b * 1024 + tid * 4;
    #pragma unroll
    for (int j = 0; j < 4; j++) {
        int i = base + j;
        if (i < NN) {
            int e = incl[t * NN + i] - deg[t * NN + i] + add;
            offs[t * NN + i] = e;
            cursor[t * NN + i] = e;
        }
    }
}

__global__ __launch_bounds__(256) void k_scatter(const int* __restrict__ src, const int* __restrict__ dst,
                                                 int* __restrict__ cursor, int* __restrict__ csr_src) {
    int idx = blockIdx.x * 256 + threadIdx.x;
    if (idx >= TT * EE) return;
    int t = idx / EE;
    int d = dst[idx];
    int pos = atomicAdd(&cursor[t * NN + d], 1);
    csr_src[t * EE + pos] = src[idx];
}

// stage 32KB (16384 ushorts) from global into LDS, whole block
__device__ __forceinline__ void stage32k(unsigned short* lw, const unsigned short* __restrict__ src, int tid) {
    #pragma unroll
    for (int i = 0; i < 8; ++i) {
        int o = i * 2048 + tid * 8;
        *(ushort8*)&lw[o] = *(const ushort8*)(src + o);
    }
}

// ---------------- split-bf16 MFMA with LDS-staged weights: Q,K,V. 128 rows/block ----------------
// launch_bounds (256,2): round-9's (256,4) squeezed VGPR to 64 -> scratch spills (+97MB HBM W, +105MB R)
__global__ __launch_bounds__(256, 2) void k_mg3(
    const float* __restrict__ x,
    const unsigned short* __restrict__ Whi, const unsigned short* __restrict__ Wlo,
    const float* __restrict__ B3,
    float* __restrict__ Q, float* __restrict__ K, float* __restrict__ V)
{
    __shared__ __align__(16) unsigned short lw[CC * CC];   // 32KB: one hi or lo half of one mat
    int tid = threadIdx.x;
    int wid = tid >> 6, l = tid & 63;
    int lan = l & 15, kb = l >> 4;
    int rb = blockIdx.x * 128 + wid * 32;

    // A fragments: 2 row-tiles x 4 k-tiles (per-wave, registers)
    bf16x8 ah[2][4], al[2][4];
    #pragma unroll
    for (int rt = 0; rt < 2; ++rt)
        #pragma unroll
        for (int kt = 0; kt < 4; ++kt)
            loadA(x, rb + rt * 16 + lan, kt, kb, ah[rt][kt], al[rt][kt]);

    #pragma unroll 1
    for (int m = 0; m < 3; ++m) {
        f32x4 acc[2][8];
        #pragma unroll
        for (int rt = 0; rt < 2; ++rt)
            #pragma unroll
            for (int nt = 0; nt < 8; ++nt)
                #pragma unroll
                for (int i = 0; i < 4; ++i) acc[rt][nt][i] = 0.f;

        // ---- hi half: acc += al*bh + ah*bh ----
        __syncthreads();
        stage32k(lw, Whi + m * CC * CC, tid);
        __syncthreads();
        #pragma unroll
        for (int kt = 0; kt < 4; ++kt)
            #pragma unroll
            for (int nt = 0; nt < 8; ++nt) {
                U8 b;
                b.u = *(const ushort8*)&lw[((kt * 8 + nt) * 64 + l) * 8];
                #pragma unroll
                for (int rt = 0; rt < 2; ++rt) {
                    acc[rt][nt] = __builtin_amdgcn_mfma_f32_16x16x32_bf16(al[rt][kt], b.b, acc[rt][nt], 0, 0, 0);
                    acc[rt][nt] = __builtin_amdgcn_mfma_f32_16x16x32_bf16(ah[rt][kt], b.b, acc[rt][nt], 0, 0, 0);
                }
            }

        // ---- lo half: acc += ah*bl ----
        __syncthreads();
        stage32k(lw, Wlo + m * CC * CC, tid);
        __syncthreads();
        #pragma unroll
        for (int kt = 0; kt < 4; ++kt)
            #pragma unroll
            for (int nt = 0; nt < 8; ++nt) {
                U8 b;
                b.u = *(const ushort8*)&lw[((kt * 8 + nt) * 64 + l) * 8];
                #pragma unroll
                for (int rt = 0; rt < 2; ++rt)
                    acc[rt][nt] = __builtin_amdgcn_mfma_f32_16x16x32_bf16(ah[rt][kt], b.b, acc[rt][nt], 0, 0, 0);
            }

        float* dst = (m == 0 ? Q : m == 1 ? K : V);
        #pragma unroll
        for (int nt = 0; nt < 8; ++nt) {
            int col = nt * 16 + lan;
            float bias = B3[m * CC + col];
            #pragma unroll
            for (int rt = 0; rt < 2; ++rt)
                #pragma unroll
                for (int i = 0; i < 4; ++i) {
                    int grow = rb + rt * 16 + kb * 4 + i;   // D: row=(l>>4)*4+reg, col=l&15 [m89]
                    if (grow < NN)
                        dst[(size_t)grow * CC + col] = acc[rt][nt][i] + bias;
                }
        }
    }
}

// ---------------- split-bf16 MFMA fusion with LDS-staged weights ----------------
__global__ __launch_bounds__(256, 2) void k_mfuse(
    const float* __restrict__ X0,
    const unsigned short* __restrict__ W0h, const unsigned short* __restrict__ W0l,
    const float* __restrict__ X1,
    const unsigned short* __restrict__ W1h, const unsigned short* __restrict__ W1l,
    const float* __restrict__ bias, float* __restrict__ out, int accum)
{
    __shared__ __align__(16) unsigned short lw[CC * CC];
    int tid = threadIdx.x;
    int wid = tid >> 6, l = tid & 63;
    int lan = l & 15, kb = l >> 4;
    int rb = blockIdx.x * 128 + wid * 32;

    f32x4 acc[2][8];
    #pragma unroll
    for (int rt = 0; rt < 2; ++rt)
        #pragma unroll
        for (int nt = 0; nt < 8; ++nt)
            #pragma unroll
            for (int i = 0; i < 4; ++i) acc[rt][nt][i] = 0.f;

    #pragma unroll 1
    for (int s = 0; s < 2; ++s) {
        const float* X = s ? X1 : X0;
        if (!X) break;
        const unsigned short* wh = s ? W1h : W0h;
        const unsigned short* wl = s ? W1l : W0l;

        bf16x8 ah[2][4], al[2][4];
        #pragma unroll
        for (int rt = 0; rt < 2; ++rt)
            #pragma unroll
            for (int kt = 0; kt < 4; ++kt)
                loadA(X, rb + rt * 16 + lan, kt, kb, ah[rt][kt], al[rt][kt]);

        __syncthreads();
        stage32k(lw, wh, tid);
        __syncthreads();
        #pragma unroll
        for (int kt = 0; kt < 4; ++kt)
            #pragma unroll
            for (int nt = 0; nt < 8; ++nt) {
                U8 b;
                b.u = *(const ushort8*)&lw[((kt * 8 + nt) * 64 + l) * 8];
                #pragma unroll
                for (int rt = 0; rt < 2; ++rt) {
                    acc[rt][nt] = __builtin_amdgcn_mfma_f32_16x16x32_bf16(al[rt][kt], b.b, acc[rt][nt], 0, 0, 0);
                    acc[rt][nt] = __builtin_amdgcn_mfma_f32_16x16x32_bf16(ah[rt][kt], b.b, acc[rt][nt], 0, 0, 0);
                }
            }

        __syncthreads();
        stage32k(lw, wl, tid);
        __syncthreads();
        #pragma unroll
        for (int kt = 0; kt < 4; ++kt)
            #pragma unroll
            for (int nt = 0; nt < 8; ++nt) {
                U8 b;
                b.u = *(const ushort8*)&lw[((kt * 8 + nt) * 64 + l) * 8];
                #pragma unroll
                for (int rt = 0; rt < 2; ++rt)
                    acc[rt][nt] = __builtin_amdgcn_mfma_f32_16x16x32_bf16(ah[rt][kt], b.b, acc[rt][nt], 0, 0, 0);
            }
    }

    #pragma unroll
    for (int nt = 0; nt < 8; ++nt) {
        int col = nt * 16 + lan;
        #pragma unroll
        for (int rt = 0; rt < 2; ++rt)
            #pragma unroll
            for (int i = 0; i < 4; ++i) {
                int grow = rb + rt * 16 + kb * 4 + i;
                if (grow < NN) {
                    float* op = out + (size_t)grow * CC + col;
                    float v = acc[rt][nt][i];
                    v += accum ? *op : bias[col];
                    *op = v;
                }
            }
    }
}

// ---------------- per-node attention aggregation -> A fp32 (unchanged) ----------------
__global__ __launch_bounds__(256) void k_agg(
    const float* __restrict__ Q, const float* __restrict__ Kx,
    const float* __restrict__ V, float* __restrict__ A,
    const int* __restrict__ offs, const int* __restrict__ deg, const int* __restrict__ csr)
{
    int wid = threadIdx.x >> 6;
    int lane = threadIdx.x & 63;
    int n = blockIdx.x * 4 + wid;
    if (n >= NN) return;
    int dg = deg[n];
    if (dg == 0) {
        A[(size_t)n * CC + lane] = 0.f;
        A[(size_t)n * CC + 64 + lane] = 0.f;
        return;
    }
    const float scale = 0.17677669529663687f;  // 1/sqrt(32)
    float q0 = Q[(size_t)n * CC + lane];
    float q1 = Q[(size_t)n * CC + 64 + lane];
    float acc0 = 0.f, acc1 = 0.f, den0 = 0.f, den1 = 0.f;
    int off = offs[n];
    for (int i = 0; i < dg; i++) {
        int s = csr[off + i];
        const float* kb = Kx + (size_t)s * CC;
        const float* vb = V + (size_t)s * CC;
        float k0 = kb[lane], k1 = kb[64 + lane];
        float v0 = vb[lane], v1 = vb[64 + lane];
        float d0 = q0 * k0, d1 = q1 * k1;
        #pragma unroll
        for (int m = 16; m >= 1; m >>= 1) {
            d0 += __shfl_xor(d0, m);
            d1 += __shfl_xor(d1, m);
        }
        float e0 = expf(d0 * scale), e1 = expf(d1 * scale);
        acc0 += e0 * v0; den0 += e0;
        acc1 += e1 * v1; den1 += e1;
    }
    A[(size_t)n * CC + lane]      = acc0 / (den0 + 1e-16f);
    A[(size_t)n * CC + 64 + lane] = acc1 / (den1 + 1e-16f);
}

extern "C" void kernel_launch(void* const* d_in, const int* in_sizes, int n_in,
                              void* d_out, int out_size, void* d_ws, size_t ws_size,
                              hipStream_t stream)
{
    const float* x   = (const float*)d_in[0];
    const int*   src = (const int*)d_in[1];
    const int*   dst = (const int*)d_in[2];
    const float* Wq  = (const float*)d_in[3];
    const float* bq  = (const float*)d_in[4];
    const float* Wk  = (const float*)d_in[5];
    const float* bk  = (const float*)d_in[6];
    const float* Wv  = (const float*)d_in[7];
    const float* bv  = (const float*)d_in[8];
    const float* Ws  = (const float*)d_in[9];
    const float* bs  = (const float*)d_in[10];
    const float* Wf  = (const float*)d_in[11];
    const float* bf  = (const float*)d_in[12];
    float* out = (float*)d_out;

    char* ws = (char*)d_ws;
    size_t o = 0;
    auto alloc = [&](size_t bytes) -> char* {
        char* p = ws + o;
        o = (o + bytes + 255) & ~(size_t)255;
        return p;
    };
    unsigned short* Whi3 = (unsigned short*)alloc((size_t)9 * CC * CC * 2);
    unsigned short* Wlo3 = (unsigned short*)alloc((size_t)9 * CC * CC * 2);
    unsigned short* Wfhi = (unsigned short*)alloc((size_t)TT * CC * CC * 2);
    unsigned short* Wflo = (unsigned short*)alloc((size_t)TT * CC * CC * 2);
    unsigned short* Wch  = (unsigned short*)alloc((size_t)CC * CC * 2);
    unsigned short* Wcl  = (unsigned short*)alloc((size_t)CC * CC * 2);
    float* Bpack  = (float*)alloc((size_t)9 * CC * 4);
    float* bconst = (float*)alloc((size_t)CC * 4);
    int* deg      = (int*)alloc((size_t)TT * NN * 4);
    int* incl     = (int*)alloc((size_t)TT * NN * 4);
    int* bsums    = (int*)alloc((size_t)TT * NCHUNK * 4);
    int* bexcl    = (int*)alloc((size_t)TT * NCHUNK * 4);
    int* offs     = (int*)alloc((size_t)TT * NN * 4);
    int* cursor   = (int*)alloc((size_t)TT * NN * 4);
    int* csr_src  = (int*)alloc((size_t)TT * EE * 4);
    float* Qb = (float*)alloc((size_t)NN * CC * 4);
    float* Kb = (float*)alloc((size_t)NN * CC * 4);
    float* Vb = (float*)alloc((size_t)NN * CC * 4);
    float* Ab = (float*)alloc((size_t)NN * CC * 4);

    hipMemsetAsync(deg, 0, (size_t)TT * NN * 4, stream);
    k_pack<<<dim3(64, 13), 256, 0, stream>>>(Wq, bq, Wk, bk, Wv, bv, Wf,
                                             Whi3, Wlo3, Wfhi, Wflo, Bpack);
    k_wcomb<<<65, 256, 0, stream>>>(Ws, bs, Wf, bf, Wch, Wcl, bconst);
    k_count<<<(TT * EE + 255) / 256, 256, 0, stream>>>(dst, deg);
    k_scan1<<<dim3(NCHUNK, TT), 256, 0, stream>>>(deg, incl, bsums);
    k_scan2<<<dim3(1, TT), 128, 0, stream>>>(bsums, bexcl);
    k_scan3<<<dim3(NCHUNK, TT), 256, 0, stream>>>(deg, incl, bexcl, offs, cursor);
    k_scatter<<<(TT * EE + 255) / 256, 256, 0, stream>>>(src, dst, cursor, csr_src);

    int gblocks = (NN + 127) / 128;   // 782
    for (int t = 0; t < TT; t++) {
        k_mg3<<<gblocks, 256, 0, stream>>>(x, Whi3 + (size_t)t * 3 * CC * CC,
                                           Wlo3 + (size_t)t * 3 * CC * CC,
                                           Bpack + t * 3 * CC, Qb, Kb, Vb);
        k_agg<<<(NN + 3) / 4, 256, 0, stream>>>(Qb, Kb, Vb, Ab,
                                                offs + t * NN, deg + t * NN, csr_src + (size_t)t * EE);
        if (t == 0)
            k_mfuse<<<gblocks, 256, 0, stream>>>(x, Wch, Wcl,
                                                 Ab, Wfhi, Wflo,
                                                 bconst, out, 0);
        else
            k_mfuse<<<gblocks, 256, 0, stream>>>(Ab, Wfhi + (size_t)t * CC * CC, Wflo + (size_t)t * CC * CC,
                                                 nullptr, nullptr, nullptr,
                                                 bconst, out, 1);
    }
}

// Round 12
// 761.528 us; speedup vs baseline: 1.3377x; 1.2061x over previous
//
#include <hip/hip_runtime.h>

#define NN 100000
#define CC 128
#define EE 200000
#define TT 3
#define NCHUNK 98   // ceil(NN/1024)

typedef __attribute__((ext_vector_type(8))) __bf16 bf16x8;
typedef __attribute__((ext_vector_type(8))) unsigned short ushort8;
typedef __attribute__((ext_vector_type(4))) float f32x4;

union U8 { ushort8 u; bf16x8 b; };

__device__ __forceinline__ unsigned short f2bf(float v) {
    unsigned u = __float_as_uint(v);
    u += 0x7fffu + ((u >> 16) & 1u);          // RNE
    return (unsigned short)(u >> 16);
}
__device__ __forceinline__ float bf2f(unsigned short h) {
    return __uint_as_float(((unsigned)h) << 16);
}
// split 8 fp32 into hi/lo bf16 fragments (a ~= hi + lo)
__device__ __forceinline__ void split8(const float* f, bf16x8& hi, bf16x8& lo) {
    U8 h, l;
    #pragma unroll
    for (int j = 0; j < 8; ++j) {
        float v = f[j];
        unsigned short hs = f2bf(v);
        h.u[j] = hs;
        l.u[j] = f2bf(v - bf2f(hs));
    }
    hi = h.b; lo = l.b;
}

// load one A row k-slice (8 fp32) and split
__device__ __forceinline__ void loadA(const float* __restrict__ X, int arow, int kt, int kb,
                                      bf16x8& hi, bf16x8& lo) {
    float tmp[8];
    if (arow < NN) {
        const float* xp = X + (size_t)arow * CC + kt * 32 + kb * 8;
        float4 p0 = *(const float4*)xp;
        float4 p1 = *(const float4*)(xp + 4);
        tmp[0] = p0.x; tmp[1] = p0.y; tmp[2] = p0.z; tmp[3] = p0.w;
        tmp[4] = p1.x; tmp[5] = p1.y; tmp[6] = p1.z; tmp[7] = p1.w;
    } else {
        #pragma unroll
        for (int j = 0; j < 8; ++j) tmp[j] = 0.f;
    }
    split8(tmp, hi, lo);
}

// fragment-major offset: frag (kt,nt), lane l, elem j  ->  ((kt*8+nt)*64+l)*8+j
// holds W[c][k] with c = nt*16+(l&15), k = kt*32+(l>>4)*8+j

// ---------------- pack: split W into bf16 hi/lo FRAGMENT-MAJOR ----------------
__global__ __launch_bounds__(256) void k_pack(
    const float* __restrict__ Wq, const float* __restrict__ bq,
    const float* __restrict__ Wk, const float* __restrict__ bk,
    const float* __restrict__ Wv, const float* __restrict__ bv,
    const float* __restrict__ Wf,
    unsigned short* __restrict__ Whi3, unsigned short* __restrict__ Wlo3,
    unsigned short* __restrict__ Wfhi, unsigned short* __restrict__ Wflo,
    float* __restrict__ Bpack)
{
    int idx = blockIdx.x * 256 + threadIdx.x;   // 0..16383
    int y = blockIdx.y;                          // 0..12
    int j  = idx & 7;
    int l  = (idx >> 3) & 63;
    int nt = (idx >> 9) & 7;
    int kt = idx >> 12;
    int c = nt * 16 + (l & 15);
    int k = kt * 32 + ((l >> 4) << 3) + j;
    if (y < 9) {
        int t = y / 3, m = y % 3;
        const float* W = (m == 0 ? Wq : m == 1 ? Wk : Wv) + t * CC * CC;
        float v = W[c * CC + k];
        unsigned short hs = f2bf(v);
        Whi3[y * CC * CC + idx] = hs;
        Wlo3[y * CC * CC + idx] = f2bf(v - bf2f(hs));
    } else if (y < 12) {
        int t = y - 9;
        float v = Wf[(size_t)c * (TT * CC) + t * CC + k];
        unsigned short hs = f2bf(v);
        Wfhi[t * CC * CC + idx] = hs;
        Wflo[t * CC * CC + idx] = f2bf(v - bf2f(hs));
    } else {
        if (idx < 9 * CC) {
            int mm = idx >> 7, cc2 = idx & 127;
            int t = mm / 3, m = mm % 3;
            const float* b = (m == 0 ? bq : m == 1 ? bk : bv);
            Bpack[idx] = b[t * CC + cc2];
        }
    }
}

// ---------------- Wcomb (skip path folded), FRAGMENT-MAJOR; bconst fp32 ----------------
__global__ __launch_bounds__(256) void k_wcomb(
    const float* __restrict__ Ws, const float* __restrict__ bs,
    const float* __restrict__ Wf, const float* __restrict__ bf,
    unsigned short* __restrict__ Wch, unsigned short* __restrict__ Wcl,
    float* __restrict__ bconst)
{
    int b = blockIdx.x;
    if (b < 64) {
        int idx = b * 256 + threadIdx.x;
        int k = idx >> 7, c = idx & 127;
        float s = 0.f;
        for (int t = 0; t < TT; ++t) {
            const float* wsp = Ws + t * CC * CC;
            const float* wfp = Wf + (size_t)c * (TT * CC) + t * CC;
            for (int j = 0; j < CC; ++j)
                s += wsp[j * CC + k] * wfp[j];
        }
        int kt = k >> 5, kb = (k >> 3) & 3, j = k & 7;
        int l = (c & 15) + (kb << 4);
        int nt = c >> 4;
        int o = (((kt * 8 + nt) * 64) + l) * 8 + j;
        unsigned short hs = f2bf(s);
        Wch[o] = hs;
        Wcl[o] = f2bf(s - bf2f(hs));
    } else {
        int c = threadIdx.x;
        if (c < CC) {
            float s = bf[c];
            for (int t = 0; t < TT; ++t) {
                const float* wfp = Wf + (size_t)c * (TT * CC) + t * CC;
                for (int j = 0; j < CC; ++j)
                    s += bs[t * CC + j] * wfp[j];
            }
            bconst[c] = s;
        }
    }
}

// ---------------- CSR build (unchanged) ----------------
__global__ __launch_bounds__(256) void k_count(const int* __restrict__ dst, int* __restrict__ deg) {
    int idx = blockIdx.x * 256 + threadIdx.x;
    if (idx >= TT * EE) return;
    int t = idx / EE;
    atomicAdd(&deg[t * NN + dst[idx]], 1);
}

__global__ __launch_bounds__(256) void k_scan1(const int* __restrict__ deg,
                                               int* __restrict__ incl, int* __restrict__ bsums) {
    int t = blockIdx.y, b = blockIdx.x, tid = threadIdx.x;
    const int* d = deg + t * NN;
    int base = b * 1024 + tid * 4;
    int v0 = (base + 0 < NN) ? d[base + 0] : 0;
    int v1 = (base + 1 < NN) ? d[base + 1] : 0;
    int v2 = (base + 2 < NN) ? d[base + 2] : 0;
    int v3 = (base + 3 < NN) ? d[base + 3] : 0;
    v1 += v0; v2 += v1; v3 += v2;
    __shared__ int lds[256];
    lds[tid] = v3;
    for (int off = 1; off < 256; off <<= 1) {
        __syncthreads();
        int x = (tid >= off) ? lds[tid - off] : 0;
        __syncthreads();
        lds[tid] += x;
    }
    __syncthreads();
    int excl = lds[tid] - v3;
    if (base + 0 < NN) incl[t * NN + base + 0] = excl + v0;
    if (base + 1 < NN) incl[t * NN + base + 1] = excl + v1;
    if (base + 2 < NN) incl[t * NN + base + 2] = excl + v2;
    if (base + 3 < NN) incl[t * NN + base + 3] = excl + v3;
    if (tid == 255) bsums[t * NCHUNK + b] = lds[255];
}

__global__ __launch_bounds__(128) void k_scan2(const int* __restrict__ bsums, int* __restrict__ bexcl) {
    int t = blockIdx.y, tid = threadIdx.x;
    __shared__ int lds[128];
    int v = (tid < NCHUNK) ? bsums[t * NCHUNK + tid] : 0;
    lds[tid] = v;
    for (int off = 1; off < 128; off <<= 1) {
        __syncthreads();
        int x = (tid >= off) ? lds[tid - off] : 0;
        __syncthreads();
        lds[tid] += x;
    }
    if (tid < NCHUNK) bexcl[t * NCHUNK + tid] = lds[tid] - v;
}

__global__ __launch_bounds__(256) void k_scan3(const int* __restrict__ deg, const int* __restrict__ incl,
                                               const int* __restrict__ bexcl,
                                               int* __restrict__ offs, int* __restrict__ cursor) {
    int t = blockIdx.y, b = blockIdx.x, tid = threadIdx.x;
    int add = bexcl[t * NCHUNK + b];
    int base = b * 1024 + tid * 4;
    #pragma unroll
    for (int j = 0; j < 4; j++) {
        int i = base + j;
        if (i < NN) {
            int e = incl[t * NN + i] - deg[t * NN + i] + add;
            offs[t * NN + i] = e;
            cursor[t * NN + i] = e;
        }
    }
}

__global__ __launch_bounds__(256) void k_scatter(const int* __restrict__ src, const int* __restrict__ dst,
                                                 int* __restrict__ cursor, int* __restrict__ csr_src) {
    int idx = blockIdx.x * 256 + threadIdx.x;
    if (idx >= TT * EE) return;
    int t = idx / EE;
    int d = dst[idx];
    int pos = atomicAdd(&cursor[t * NN + d], 1);
    csr_src[t * EE + pos] = src[idx];
}

// stage 32KB (16384 ushorts) from global into LDS, whole block
__device__ __forceinline__ void stage32k(unsigned short* lw, const unsigned short* __restrict__ src, int tid) {
    #pragma unroll
    for (int i = 0; i < 8; ++i) {
        int o = i * 2048 + tid * 8;
        *(ushort8*)&lw[o] = *(const ushort8*)(src + o);
    }
}

// ---------------- split-bf16 MFMA, LDS weights: Q,K,V. 64 rows/block, 16 rows/wave ----------------
// 16 rows/wave: acc 32 + A-frags 32 + temps ~= 95 regs -> (256,4) is spill-free (round-9's
// spill was the 32-row variant's ~160 regs under the 128 cap). 4 blocks/CU for latency hiding.
__global__ __launch_bounds__(256, 4) void k_mg3(
    const float* __restrict__ x,
    const unsigned short* __restrict__ Whi, const unsigned short* __restrict__ Wlo,
    const float* __restrict__ B3,
    float* __restrict__ Q, float* __restrict__ K, float* __restrict__ V)
{
    __shared__ __align__(16) unsigned short lw[CC * CC];   // 32KB: one hi or lo half of one mat
    int tid = threadIdx.x;
    int wid = tid >> 6, l = tid & 63;
    int lan = l & 15, kb = l >> 4;
    int rb = blockIdx.x * 64 + wid * 16;

    // A fragments: 4 k-tiles (per-wave, registers)
    bf16x8 ah[4], al[4];
    #pragma unroll
    for (int kt = 0; kt < 4; ++kt)
        loadA(x, rb + lan, kt, kb, ah[kt], al[kt]);

    #pragma unroll 1
    for (int m = 0; m < 3; ++m) {
        f32x4 acc[8];
        #pragma unroll
        for (int nt = 0; nt < 8; ++nt)
            #pragma unroll
            for (int i = 0; i < 4; ++i) acc[nt][i] = 0.f;

        // ---- hi half: acc += al*bh + ah*bh ----
        __syncthreads();
        stage32k(lw, Whi + m * CC * CC, tid);
        __syncthreads();
        #pragma unroll
        for (int kt = 0; kt < 4; ++kt)
            #pragma unroll
            for (int nt = 0; nt < 8; ++nt) {
                U8 b;
                b.u = *(const ushort8*)&lw[((kt * 8 + nt) * 64 + l) * 8];
                acc[nt] = __builtin_amdgcn_mfma_f32_16x16x32_bf16(al[kt], b.b, acc[nt], 0, 0, 0);
                acc[nt] = __builtin_amdgcn_mfma_f32_16x16x32_bf16(ah[kt], b.b, acc[nt], 0, 0, 0);
            }

        // ---- lo half: acc += ah*bl ----
        __syncthreads();
        stage32k(lw, Wlo + m * CC * CC, tid);
        __syncthreads();
        #pragma unroll
        for (int kt = 0; kt < 4; ++kt)
            #pragma unroll
            for (int nt = 0; nt < 8; ++nt) {
                U8 b;
                b.u = *(const ushort8*)&lw[((kt * 8 + nt) * 64 + l) * 8];
                acc[nt] = __builtin_amdgcn_mfma_f32_16x16x32_bf16(ah[kt], b.b, acc[nt], 0, 0, 0);
            }

        float* dst = (m == 0 ? Q : m == 1 ? K : V);
        #pragma unroll
        for (int nt = 0; nt < 8; ++nt) {
            int col = nt * 16 + lan;
            float bias = B3[m * CC + col];
            #pragma unroll
            for (int i = 0; i < 4; ++i) {
                int grow = rb + kb * 4 + i;     // D: row=(l>>4)*4+reg, col=l&15 [m89]
                if (grow < NN)
                    dst[(size_t)grow * CC + col] = acc[nt][i] + bias;
            }
        }
    }
}

// ---------------- split-bf16 MFMA fusion, up to 4 sources: out (+)= sum_s Xs@Ws (+ bconst) ----------------
__global__ __launch_bounds__(256, 4) void k_mfuse(
    const float* __restrict__ X0, const unsigned short* __restrict__ W0h, const unsigned short* __restrict__ W0l,
    const float* __restrict__ X1, const unsigned short* __restrict__ W1h, const unsigned short* __restrict__ W1l,
    const float* __restrict__ X2, const unsigned short* __restrict__ W2h, const unsigned short* __restrict__ W2l,
    const float* __restrict__ X3, const unsigned short* __restrict__ W3h, const unsigned short* __restrict__ W3l,
    const float* __restrict__ bias, float* __restrict__ out, int accum)
{
    __shared__ __align__(16) unsigned short lw[CC * CC];
    int tid = threadIdx.x;
    int wid = tid >> 6, l = tid & 63;
    int lan = l & 15, kb = l >> 4;
    int rb = blockIdx.x * 64 + wid * 16;

    f32x4 acc[8];
    #pragma unroll
    for (int nt = 0; nt < 8; ++nt)
        #pragma unroll
        for (int i = 0; i < 4; ++i) acc[nt][i] = 0.f;

    #pragma unroll 1
    for (int s = 0; s < 4; ++s) {
        const float* X = (s == 0 ? X0 : s == 1 ? X1 : s == 2 ? X2 : X3);
        if (!X) break;
        const unsigned short* wh = (s == 0 ? W0h : s == 1 ? W1h : s == 2 ? W2h : W3h);
        const unsigned short* wl = (s == 0 ? W0l : s == 1 ? W1l : s == 2 ? W2l : W3l);

        bf16x8 ah[4], al[4];
        #pragma unroll
        for (int kt = 0; kt < 4; ++kt)
            loadA(X, rb + lan, kt, kb, ah[kt], al[kt]);

        __syncthreads();
        stage32k(lw, wh, tid);
        __syncthreads();
        #pragma unroll
        for (int kt = 0; kt < 4; ++kt)
            #pragma unroll
            for (int nt = 0; nt < 8; ++nt) {
                U8 b;
                b.u = *(const ushort8*)&lw[((kt * 8 + nt) * 64 + l) * 8];
                acc[nt] = __builtin_amdgcn_mfma_f32_16x16x32_bf16(al[kt], b.b, acc[nt], 0, 0, 0);
                acc[nt] = __builtin_amdgcn_mfma_f32_16x16x32_bf16(ah[kt], b.b, acc[nt], 0, 0, 0);
            }

        __syncthreads();
        stage32k(lw, wl, tid);
        __syncthreads();
        #pragma unroll
        for (int kt = 0; kt < 4; ++kt)
            #pragma unroll
            for (int nt = 0; nt < 8; ++nt) {
                U8 b;
                b.u = *(const ushort8*)&lw[((kt * 8 + nt) * 64 + l) * 8];
                acc[nt] = __builtin_amdgcn_mfma_f32_16x16x32_bf16(ah[kt], b.b, acc[nt], 0, 0, 0);
            }
    }

    #pragma unroll
    for (int nt = 0; nt < 8; ++nt) {
        int col = nt * 16 + lan;
        #pragma unroll
        for (int i = 0; i < 4; ++i) {
            int grow = rb + kb * 4 + i;
            if (grow < NN) {
                float* op = out + (size_t)grow * CC + col;
                float v = acc[nt][i];
                v += accum ? *op : bias[col];
                *op = v;
            }
        }
    }
}

// ---------------- per-node attention aggregation -> A fp32 (unchanged) ----------------
__global__ __launch_bounds__(256) void k_agg(
    const float* __restrict__ Q, const float* __restrict__ Kx,
    const float* __restrict__ V, float* __restrict__ A,
    const int* __restrict__ offs, const int* __restrict__ deg, const int* __restrict__ csr)
{
    int wid = threadIdx.x >> 6;
    int lane = threadIdx.x & 63;
    int n = blockIdx.x * 4 + wid;
    if (n >= NN) return;
    int dg = deg[n];
    if (dg == 0) {
        A[(size_t)n * CC + lane] = 0.f;
        A[(size_t)n * CC + 64 + lane] = 0.f;
        return;
    }
    const float scale = 0.17677669529663687f;  // 1/sqrt(32)
    float q0 = Q[(size_t)n * CC + lane];
    float q1 = Q[(size_t)n * CC + 64 + lane];
    float acc0 = 0.f, acc1 = 0.f, den0 = 0.f, den1 = 0.f;
    int off = offs[n];
    for (int i = 0; i < dg; i++) {
        int s = csr[off + i];
        const float* kb = Kx + (size_t)s * CC;
        const float* vb = V + (size_t)s * CC;
        float k0 = kb[lane], k1 = kb[64 + lane];
        float v0 = vb[lane], v1 = vb[64 + lane];
        float d0 = q0 * k0, d1 = q1 * k1;
        #pragma unroll
        for (int m = 16; m >= 1; m >>= 1) {
            d0 += __shfl_xor(d0, m);
            d1 += __shfl_xor(d1, m);
        }
        float e0 = expf(d0 * scale), e1 = expf(d1 * scale);
        acc0 += e0 * v0; den0 += e0;
        acc1 += e1 * v1; den1 += e1;
    }
    A[(size_t)n * CC + lane]      = acc0 / (den0 + 1e-16f);
    A[(size_t)n * CC + 64 + lane] = acc1 / (den1 + 1e-16f);
}

extern "C" void kernel_launch(void* const* d_in, const int* in_sizes, int n_in,
                              void* d_out, int out_size, void* d_ws, size_t ws_size,
                              hipStream_t stream)
{
    const float* x   = (const float*)d_in[0];
    const int*   src = (const int*)d_in[1];
    const int*   dst = (const int*)d_in[2];
    const float* Wq  = (const float*)d_in[3];
    const float* bq  = (const float*)d_in[4];
    const float* Wk  = (const float*)d_in[5];
    const float* bk  = (const float*)d_in[6];
    const float* Wv  = (const float*)d_in[7];
    const float* bv  = (const float*)d_in[8];
    const float* Ws  = (const float*)d_in[9];
    const float* bs  = (const float*)d_in[10];
    const float* Wf  = (const float*)d_in[11];
    const float* bf  = (const float*)d_in[12];
    float* out = (float*)d_out;

    char* ws = (char*)d_ws;
    size_t o = 0;
    auto alloc = [&](size_t bytes) -> char* {
        char* p = ws + o;
        o = (o + bytes + 255) & ~(size_t)255;
        return p;
    };
    unsigned short* Whi3 = (unsigned short*)alloc((size_t)9 * CC * CC * 2);
    unsigned short* Wlo3 = (unsigned short*)alloc((size_t)9 * CC * CC * 2);
    unsigned short* Wfhi = (unsigned short*)alloc((size_t)TT * CC * CC * 2);
    unsigned short* Wflo = (unsigned short*)alloc((size_t)TT * CC * CC * 2);
    unsigned short* Wch  = (unsigned short*)alloc((size_t)CC * CC * 2);
    unsigned short* Wcl  = (unsigned short*)alloc((size_t)CC * CC * 2);
    float* Bpack  = (float*)alloc((size_t)9 * CC * 4);
    float* bconst = (float*)alloc((size_t)CC * 4);
    int* deg      = (int*)alloc((size_t)TT * NN * 4);
    int* incl     = (int*)alloc((size_t)TT * NN * 4);
    int* bsums    = (int*)alloc((size_t)TT * NCHUNK * 4);
    int* bexcl    = (int*)alloc((size_t)TT * NCHUNK * 4);
    int* offs     = (int*)alloc((size_t)TT * NN * 4);
    int* cursor   = (int*)alloc((size_t)TT * NN * 4);
    int* csr_src  = (int*)alloc((size_t)TT * EE * 4);
    float* Qb = (float*)alloc((size_t)NN * CC * 4);
    float* Kb = (float*)alloc((size_t)NN * CC * 4);
    float* Vb = (float*)alloc((size_t)NN * CC * 4);
    float* A0 = (float*)alloc((size_t)NN * CC * 4);
    // 3-A path needs +2 x 51.2MB beyond the proven ~215MB layout; fall back if ws too small
    size_t needA3 = o + 2 * ((size_t)NN * CC * 4 + 256);
    bool use3 = (ws_size >= needA3);
    float* A1 = use3 ? (float*)alloc((size_t)NN * CC * 4) : A0;
    float* A2 = use3 ? (float*)alloc((size_t)NN * CC * 4) : A0;

    hipMemsetAsync(deg, 0, (size_t)TT * NN * 4, stream);
    k_pack<<<dim3(64, 13), 256, 0, stream>>>(Wq, bq, Wk, bk, Wv, bv, Wf,
                                             Whi3, Wlo3, Wfhi, Wflo, Bpack);
    k_wcomb<<<65, 256, 0, stream>>>(Ws, bs, Wf, bf, Wch, Wcl, bconst);
    k_count<<<(TT * EE + 255) / 256, 256, 0, stream>>>(dst, deg);
    k_scan1<<<dim3(NCHUNK, TT), 256, 0, stream>>>(deg, incl, bsums);
    k_scan2<<<dim3(1, TT), 128, 0, stream>>>(bsums, bexcl);
    k_scan3<<<dim3(NCHUNK, TT), 256, 0, stream>>>(deg, incl, bexcl, offs, cursor);
    k_scatter<<<(TT * EE + 255) / 256, 256, 0, stream>>>(src, dst, cursor, csr_src);

    int gblocks = (NN + 63) / 64;   // 1563
    if (use3) {
        float* As[3] = {A0, A1, A2};
        for (int t = 0; t < TT; t++) {
            k_mg3<<<gblocks, 256, 0, stream>>>(x, Whi3 + (size_t)t * 3 * CC * CC,
                                               Wlo3 + (size_t)t * 3 * CC * CC,
                                               Bpack + t * 3 * CC, Qb, Kb, Vb);
            k_agg<<<(NN + 3) / 4, 256, 0, stream>>>(Qb, Kb, Vb, As[t],
                                                    offs + t * NN, deg + t * NN, csr_src + (size_t)t * EE);
        }
        k_mfuse<<<gblocks, 256, 0, stream>>>(
            x, Wch, Wcl,
            A0, Wfhi, Wflo,
            A1, Wfhi + (size_t)CC * CC, Wflo + (size_t)CC * CC,
            A2, Wfhi + (size_t)2 * CC * CC, Wflo + (size_t)2 * CC * CC,
            bconst, out, 0);
    } else {
        for (int t = 0; t < TT; t++) {
            k_mg3<<<gblocks, 256, 0, stream>>>(x, Whi3 + (size_t)t * 3 * CC * CC,
                                               Wlo3 + (size_t)t * 3 * CC * CC,
                                               Bpack + t * 3 * CC, Qb, Kb, Vb);
            k_agg<<<(NN + 3) / 4, 256, 0, stream>>>(Qb, Kb, Vb, A0,
                                                    offs + t * NN, deg + t * NN, csr_src + (size_t)t * EE);
            if (t == 0)
                k_mfuse<<<gblocks, 256, 0, stream>>>(
                    x, Wch, Wcl, A0, Wfhi, Wflo,
                    nullptr, nullptr, nullptr, nullptr, nullptr, nullptr,
                    bconst, out, 0);
            else
                k_mfuse<<<gblocks, 256, 0, stream>>>(
                    A0, Wfhi + (size_t)t * CC * CC, Wflo + (size_t)t * CC * CC,
                    nullptr, nullptr, nullptr, nullptr, nullptr, nullptr,
                    nullptr, nullptr, nullptr,
                    bconst, out, 1);
        }
    }
}